// Round 2
// baseline (459.296 us; speedup 1.0000x reference)
//
#include <hip/hip_runtime.h>

#define D_PIX 16384      // FH*FW
#define NSMP  9
#define TP    64         // pixels per block
#define RS    136        // LDS row stride (128 ch + 8 pad), elements

typedef __attribute__((ext_vector_type(8))) short s16x8;   // 8 bf16 (4 VGPRs) - MFMA A/B frag
typedef __attribute__((ext_vector_type(4))) short s16x4;
typedef __attribute__((ext_vector_type(4))) float f32x4;   // MFMA C/D frag + global fp32 loads

__device__ __forceinline__ short f2b(float f) {
    union { float f; unsigned u; } c; c.f = f;
    unsigned r = (c.u + 0x7FFFu + ((c.u >> 16) & 1u)) >> 16;   // RNE
    return (short)r;
}

// Block: 256 threads = 4 waves. Covers TP=64 pixels of one batch image.
// Wave w owns heads {2w, 2w+1} for all 64 px.
// LDS tiles are bf16 [px][ch] (converted+transposed from global fp32 [ch][px])
// so MFMA B-frags (K = channels, contiguous per lane) are single ds_read_b128.
__global__ __launch_bounds__(256, 2)
void deform_attn_kernel(const float* __restrict__ q,
                        const float* __restrict__ kv,
                        const float* __restrict__ Wq,
                        const float* __restrict__ bq,
                        const float* __restrict__ Wk,
                        const float* __restrict__ bk,
                        const float* __restrict__ Wv,
                        const float* __restrict__ bv,
                        float* __restrict__ out)
{
    __shared__ short ldsb[2][TP * RS];   // 2 x 17408 B

    const int tid  = threadIdx.x;
    const int bid  = blockIdx.x;
    const int b    = bid >> 8;            // 256 blocks per batch image
    const int px0  = (bid & 255) * TP;
    const int lane = tid & 63;
    const int w    = tid >> 6;            // wave id 0..3
    const int r    = lane & 15;           // MFMA col (pixel within 16-tile)
    const int quad = lane >> 4;           // MFMA quad

    // ---- staging mapping: thread -> 4 channels x 8 pixels ----
    const int pxb = (tid & 7) * 8;        // pixel base 0..56
    const int chb = (tid >> 3) * 4;       // channel base 0..124

    f32x4 pref[4][2];                     // staged fp32 (4 ch x 8 px)
    auto stage_load = [&](const float* base, int chstride) {
        #pragma unroll
        for (int j = 0; j < 4; ++j) {
            const float* p = base + (long)(chb + j) * chstride + pxb;
            pref[j][0] = *(const f32x4*)p;
            pref[j][1] = *(const f32x4*)(p + 4);
        }
    };
    auto stage_write = [&](short* buf) {
        #pragma unroll
        for (int i = 0; i < 8; ++i) {
            s16x4 v4 = { f2b(pref[0][i >> 2][i & 3]), f2b(pref[1][i >> 2][i & 3]),
                         f2b(pref[2][i >> 2][i & 3]), f2b(pref[3][i >> 2][i & 3]) };
            *(s16x4*)(buf + (pxb + i) * RS + chb) = v4;   // ds_write_b64
        }
    };
    auto load_bfrags = [&](const short* buf, int n, s16x8* bfr) {
        #pragma unroll
        for (int ks = 0; ks < 4; ++ks)    // B[k][nn]: k = ks*32 + quad*8 + j, nn = r
            bfr[ks] = *(const s16x8*)(buf + (n * 16 + r) * RS + ks * 32 + quad * 8);
    };
    auto load_wfrag = [&](const float* W, int o, int ks) -> s16x8 {
        const float* p = W + o * 128 + ks * 32 + quad * 8;
        f32x4 a = *(const f32x4*)p;
        f32x4 c = *(const f32x4*)(p + 4);
        s16x8 f = { f2b(a[0]), f2b(a[1]), f2b(a[2]), f2b(a[3]),
                    f2b(c[0]), f2b(c[1]), f2b(c[2]), f2b(c[3]) };
        return f;
    };

    // ---- persistent per-wave weight fragments (A operand: A[m=lane&15][k=quad*8+j]) ----
    s16x8 wkF[2][4], wvF[2][4];
    float bkf[2][4], bvf[2][4], bqf[2][4];
    #pragma unroll
    for (int m = 0; m < 2; ++m) {
        const int o = (2 * w + m) * 16 + r;          // weight row = output channel
        #pragma unroll
        for (int ks = 0; ks < 4; ++ks) {
            wkF[m][ks] = load_wfrag(Wk, o, ks);
            wvF[m][ks] = load_wfrag(Wv, o, ks);
        }
        const int ob = (2 * w + m) * 16 + quad * 4;  // C/D row base for this lane
        #pragma unroll
        for (int rr = 0; rr < 4; ++rr) {
            bqf[m][rr] = bq[ob + rr];
            bkf[m][rr] = bk[ob + rr];
            bvf[m][rr] = bv[ob + rr];
        }
    }

    float qp[2][4][4];      // q projection, C/D layout, [head][ntile][reg]
    float oacc[2][4][4];    // output accumulator
    float lsum[2][4];       // softmax denominator
    #pragma unroll
    for (int m = 0; m < 2; ++m)
        #pragma unroll
        for (int n = 0; n < 4; ++n) {
            lsum[m][n] = 0.f;
            #pragma unroll
            for (int rr = 0; rr < 4; ++rr) oacc[m][n][rr] = 0.f;
        }

    const float* qbase  = q  + (long)(b * 128) * D_PIX + px0;        // ch stride D_PIX
    const float* kvbase = kv + (long)(b * 128) * NSMP * D_PIX + px0; // ch stride 9*D_PIX

    // ---- prologue: stage q tile, compute qp, prefetch sample 0 ----
    stage_load(qbase, D_PIX);
    stage_write(ldsb[0]);
    __syncthreads();

    stage_load(kvbase, NSMP * D_PIX);     // sample 0
    {
        s16x8 wqF[2][4];
        #pragma unroll
        for (int m = 0; m < 2; ++m) {
            const int o = (2 * w + m) * 16 + r;
            #pragma unroll
            for (int ks = 0; ks < 4; ++ks)
                wqF[m][ks] = load_wfrag(Wq, o, ks);
        }
        #pragma unroll
        for (int n = 0; n < 4; ++n) {
            s16x8 bfr[4];
            load_bfrags(ldsb[0], n, bfr);
            #pragma unroll
            for (int m = 0; m < 2; ++m) {
                f32x4 acc = {0.f, 0.f, 0.f, 0.f};
                #pragma unroll
                for (int ks = 0; ks < 4; ++ks)
                    acc = __builtin_amdgcn_mfma_f32_16x16x32_bf16(wqF[m][ks], bfr[ks], acc, 0, 0, 0);
                #pragma unroll
                for (int rr = 0; rr < 4; ++rr) qp[m][n][rr] = acc[rr] + bqf[m][rr];
            }
        }
    }
    stage_write(ldsb[1]);
    __syncthreads();

    // ---- main loop over 9 samples ----
    for (int s = 0; s < NSMP; ++s) {
        if (s < NSMP - 1) stage_load(kvbase + (s + 1) * D_PIX, NSMP * D_PIX);
        const short* buf = ldsb[(s + 1) & 1];
        #pragma unroll
        for (int n = 0; n < 4; ++n) {
            s16x8 bfr[4];
            load_bfrags(buf, n, bfr);
            #pragma unroll
            for (int m = 0; m < 2; ++m) {
                f32x4 kacc = {0.f, 0.f, 0.f, 0.f};
                f32x4 vacc = {0.f, 0.f, 0.f, 0.f};
                #pragma unroll
                for (int ks = 0; ks < 4; ++ks) {
                    kacc = __builtin_amdgcn_mfma_f32_16x16x32_bf16(wkF[m][ks], bfr[ks], kacc, 0, 0, 0);
                    vacc = __builtin_amdgcn_mfma_f32_16x16x32_bf16(wvF[m][ks], bfr[ks], vacc, 0, 0, 0);
                }
                // logit: dot over the head's 16 channels = in-lane (4 regs) + cross-quad reduce
                float pf = 0.f;
                #pragma unroll
                for (int rr = 0; rr < 4; ++rr) pf += qp[m][n][rr] * (kacc[rr] + bkf[m][rr]);
                pf += __shfl_xor(pf, 16, 64);
                pf += __shfl_xor(pf, 32, 64);
                const float e = __expf(pf * 0.25f);   // SCALE = 16^-0.5; |logit| small, no max-sub
                lsum[m][n] += e;
                #pragma unroll
                for (int rr = 0; rr < 4; ++rr) oacc[m][n][rr] += e * (vacc[rr] + bvf[m][rr]);
            }
        }
        if (s < NSMP - 1) stage_write(ldsb[s & 1]);
        __syncthreads();
    }

    // ---- epilogue: divide by denom, store fp32 ----
    #pragma unroll
    for (int m = 0; m < 2; ++m) {
        #pragma unroll
        for (int n = 0; n < 4; ++n) {
            const float inv = 1.f / lsum[m][n];
            #pragma unroll
            for (int rr = 0; rr < 4; ++rr) {
                const int o = (2 * w + m) * 16 + quad * 4 + rr;
                out[(long)(b * 128 + o) * D_PIX + px0 + n * 16 + r] = oacc[m][n][rr] * inv;
            }
        }
    }
}

extern "C" void kernel_launch(void* const* d_in, const int* in_sizes, int n_in,
                              void* d_out, int out_size, void* d_ws, size_t ws_size,
                              hipStream_t stream) {
    const float* q  = (const float*)d_in[0];
    const float* kv = (const float*)d_in[1];
    const float* Wq = (const float*)d_in[2];
    const float* bq = (const float*)d_in[3];
    const float* Wk = (const float*)d_in[4];
    const float* bk = (const float*)d_in[5];
    const float* Wv = (const float*)d_in[6];
    const float* bv = (const float*)d_in[7];
    float* out = (float*)d_out;

    dim3 grid(1024);   // 4 batches * (16384/64) pixel tiles
    dim3 block(256);
    hipLaunchKernelGGL(deform_attn_kernel, grid, block, 0, stream,
                       q, kv, Wq, bq, Wk, bk, Wv, bv, out);
}